// Round 11
// baseline (182.643 us; speedup 1.0000x reference)
//
#include <hip/hip_runtime.h>
#include <math.h>

#define BB 4
#define LL 1024
#define SS 1024
#define DM 1024
#define HH 16
#define DKH 64
#define NH 1024
#define QK_ALPHA 0.1803368801f   // 0.125 * log2(e); folded into Q so exp = exp2

typedef __attribute__((ext_vector_type(8))) short bf16x8;
typedef __attribute__((ext_vector_type(4))) float f32x4;
typedef unsigned short ushort_t;
typedef unsigned int uint_t;

#define MFMA16(a, b, c) __builtin_amdgcn_mfma_f32_16x16x32_bf16((a), (b), (c), 0, 0, 0)

__device__ __forceinline__ ushort_t f2b(float f) {
    union { float f; uint_t u; } x; x.f = f;
    uint_t r = x.u + 0x7fffu + ((x.u >> 16) & 1u);   // RNE to bf16
    return (ushort_t)(r >> 16);
}

__device__ __forceinline__ float b2f(ushort_t v) {
    union { float f; uint_t u; } x; x.u = ((uint_t)v) << 16;
    return x.f;
}

__device__ __forceinline__ void gload_lds16(const void* g, void* l) {
    __builtin_amdgcn_global_load_lds(
        (const __attribute__((address_space(1))) unsigned int*)g,
        (__attribute__((address_space(3))) unsigned int*)l, 16, 0, 0);
}

// Bijective XCD swizzle (nwg % 8 == 0)
__device__ __forceinline__ int xcd_swz(int lin, int nwg) {
    return (lin & 7) * (nwg >> 3) + (lin >> 3);
}

// ---------------------------------------------------------------------------
// Prep: fp32 -> bf16; gate read ONCE serving all three gated weights.
// ---------------------------------------------------------------------------
__device__ __forceinline__ void cvt8(const float* src, ushort_t* dst, const float* g2) {
    float4 a  = *(const float4*)(src);
    float4 b4 = *(const float4*)(src + 4);
    if (g2) {
        float4 ga = *(const float4*)(g2);
        float4 gb = *(const float4*)(g2 + 4);
        a.x *= ga.x; a.y *= ga.y; a.z *= ga.z; a.w *= ga.w;
        b4.x *= gb.x; b4.y *= gb.y; b4.z *= gb.z; b4.w *= gb.w;
    }
    uint4 o;
    o.x = f2b(a.x)  | ((uint_t)f2b(a.y)  << 16);
    o.y = f2b(a.z)  | ((uint_t)f2b(a.w)  << 16);
    o.z = f2b(b4.x) | ((uint_t)f2b(b4.y) << 16);
    o.w = f2b(b4.z) | ((uint_t)f2b(b4.w) << 16);
    *(uint4*)dst = o;
}

__global__ __launch_bounds__(256) void prep_kernel(
    const float* __restrict__ q, const float* __restrict__ k, const float* __restrict__ v,
    const float* __restrict__ gate,
    const float* __restrict__ Wq, const float* __restrict__ Wk, const float* __restrict__ Wv,
    const float* __restrict__ Wo,
    ushort_t* __restrict__ Xq, ushort_t* __restrict__ Xk, ushort_t* __restrict__ Xv,
    ushort_t* __restrict__ Gq, ushort_t* __restrict__ Gk, ushort_t* __restrict__ Gv,
    ushort_t* __restrict__ Wo2)
{
    const int XCH = 3 * 524288;
    const int GCH = 524288;
    const int WCH = 131072;
    for (int c = blockIdx.x * 256 + threadIdx.x; c < XCH + GCH + WCH; c += gridDim.x * 256) {
        if (c < XCH) {
            int r = c >> 19;
            int e = (c & 524287) * 8;
            cvt8((r == 0 ? q : r == 1 ? k : v) + e,
                 (r == 0 ? Xq : r == 1 ? Xk : Xv) + e, nullptr);
        } else if (c < XCH + GCH) {
            int e = (c - XCH) * 8;          // e = b*1048576 + nm
            int nm = e & 1048575;
            const float* g2 = gate + e;
            cvt8(Wq + nm, Gq + e, g2);
            cvt8(Wk + nm, Gk + e, g2);
            cvt8(Wv + nm, Gv + e, g2);
        } else {
            int e = (c - XCH - GCH) * 8;
            cvt8(Wo + e, Wo2 + e, nullptr);
        }
    }
}

// ---------------------------------------------------------------------------
// Merged Q/K/Vt GEMM, 1-D grid + XCD chunking. 128x128 tile, BK=64, 4 waves.
// Q output (g==0) pre-scaled by QK_ALPHA so attn's exp is a bare exp2.
// ---------------------------------------------------------------------------
__global__ __launch_bounds__(256) void qkv_gemm(
    const ushort_t* __restrict__ Xq, const ushort_t* __restrict__ Gq, const float* __restrict__ bq,
    const ushort_t* __restrict__ Xk, const ushort_t* __restrict__ Gk, const float* __restrict__ bk,
    const ushort_t* __restrict__ Xv, const ushort_t* __restrict__ Gv, const float* __restrict__ bv,
    ushort_t* __restrict__ Qb, ushort_t* __restrict__ Kb, ushort_t* __restrict__ Vt,
    int mode)
{
    __shared__ ushort_t As[128 * 64];
    __shared__ ushort_t Bs[128 * 64];
    const int p  = xcd_swz(blockIdx.x, gridDim.x);
    const int g2 = p >> 6;
    const int r  = p & 63;
    int b, g;
    if (mode == 0)      { b = g2 / 3;  g = g2 % 3; }
    else if (mode == 1) { b = g2 >> 1; g = g2 & 1; }
    else                { b = g2;      g = 2;      }
    const size_t off = (size_t)b * 1048576;
    const ushort_t *A, *B; const float* bias; ushort_t* C; bool brow;
    if (g == 0)      { A = Xq + off; B = Gq + off; bias = bq; C = Qb + off; brow = false; }
    else if (g == 1) { A = Xk + off; B = Gk + off; bias = bk; C = Kb + off; brow = false; }
    else             { A = Gv + off; B = Xv + off; bias = bv; C = Vt + off; brow = true;  }
    const float oscale = (g == 0) ? QK_ALPHA : 1.0f;

    const int bm = (r >> 3) * 128;
    const int bn = (r & 7) * 128;
    const int tid = threadIdx.x;
    const int lane = tid & 63;
    const int w = tid >> 6;
    const int wr = w >> 1, wc = w & 1;
    const int lr = lane & 15, lk = lane >> 4;

    f32x4 acc[4][4];
    #pragma unroll
    for (int i = 0; i < 4; ++i)
        #pragma unroll
        for (int j = 0; j < 4; ++j)
            acc[i][j] = (f32x4){0.f, 0.f, 0.f, 0.f};

    for (int k0 = 0; k0 < 1024; k0 += 64) {
        #pragma unroll
        for (int pp = 0; pp < 4; ++pp) {
            int f = pp * 256 + tid;
            int row = f >> 3, seg = f & 7;
            int kb2 = (seg * 8) ^ ((row & 7) * 8);
            gload_lds16(A + (size_t)(bm + row) * 1024 + k0 + kb2,
                        (char*)As + ((pp * 256 + (w << 6)) << 4));
            gload_lds16(B + (size_t)(bn + row) * 1024 + k0 + kb2,
                        (char*)Bs + ((pp * 256 + (w << 6)) << 4));
        }
        __syncthreads();
        #pragma unroll
        for (int kk = 0; kk < 2; ++kk) {
            bf16x8 af[4], bfr[4];
            #pragma unroll
            for (int i = 0; i < 4; ++i) {
                int row = wr * 64 + i * 16 + lr;
                af[i] = *(const bf16x8*)&As[row * 64 + ((lk * 8 + kk * 32) ^ ((row & 7) * 8))];
            }
            #pragma unroll
            for (int j = 0; j < 4; ++j) {
                int row = wc * 64 + j * 16 + lr;
                bfr[j] = *(const bf16x8*)&Bs[row * 64 + ((lk * 8 + kk * 32) ^ ((row & 7) * 8))];
            }
            #pragma unroll
            for (int i = 0; i < 4; ++i)
                #pragma unroll
                for (int j = 0; j < 4; ++j)
                    acc[i][j] = MFMA16(af[i], bfr[j], acc[i][j]);
        }
        __syncthreads();
    }

    #pragma unroll
    for (int i = 0; i < 4; ++i)
        #pragma unroll
        for (int j = 0; j < 4; ++j)
            #pragma unroll
            for (int rr = 0; rr < 4; ++rr) {
                int row = bm + wr * 64 + i * 16 + lk * 4 + rr;
                int col = bn + wc * 64 + j * 16 + lr;
                float vv = (acc[i][j][rr] + bias[brow ? row : col]) * oscale;
                C[(size_t)row * 1024 + col] = f2b(vv);
            }
}

// ---------------------------------------------------------------------------
// Fused QK^T + softmax + attn-write + PV. 4 waves x 32 q-rows (2 A-subtiles
// per wave): each staged K/V fragment read from LDS feeds TWO MFMAs, halving
// per-CU LDS traffic vs the 8-wave/16-row version (the measured bottleneck).
// 256 threads, 128 q-rows/block, grid 512. LDS: K dbuf 16K + V dbuf 16K +
// Ps 16K = 48KB -> 3 blocks/CU = 12 waves/CU.
// ---------------------------------------------------------------------------
__global__ __launch_bounds__(256) void fused_attn_kernel(
    const ushort_t* __restrict__ Q, const ushort_t* __restrict__ Kmat,
    const ushort_t* __restrict__ Vt, float* __restrict__ attn,
    ushort_t* __restrict__ ctx)
{
    __shared__ ushort_t K2[2][64 * 64];
    __shared__ ushort_t V2[2][64 * 64];
    __shared__ ushort_t Ps[4 * 2048];
    const int p  = xcd_swz(blockIdx.x, gridDim.x);
    const int bh = p >> 3;
    const int b  = bh >> 4;
    const int h  = bh & 15;
    const int r0 = (p & 7) * 128;
    const int tid = threadIdx.x, lane = tid & 63, w = tid >> 6;   // w in [0,4)
    const int lr = lane & 15, lk = lane >> 4;

    bf16x8 aq[2][2];   // [subtile i][kk]
    #pragma unroll
    for (int i = 0; i < 2; ++i) {
        const ushort_t* Qrow = Q + ((size_t)b * LL + r0 + w * 32 + i * 16 + lr) * NH + h * DKH;
        aq[i][0] = *(const bf16x8*)(Qrow + lk * 8);
        aq[i][1] = *(const bf16x8*)(Qrow + lk * 8 + 32);
    }
    const ushort_t* Kp = Kmat + (size_t)b * SS * NH + h * DKH;       // [s][dk], stride NH
    const ushort_t* Vp = Vt + ((size_t)b * NH + h * DKH) * SS;       // [dk][s], stride SS
    ushort_t* Psw = Ps + w * 2048;                                    // 32 rows x 64

    const int srow = tid >> 3;           // 0..31 (+32 second half)
    const int sseg = tid & 7;
    const int skb  = (sseg * 8) ^ ((srow & 7) * 8);
    const int skb1 = (sseg * 8) ^ (((srow + 32) & 7) * 8);

#define STAGE_K(t, buf)                                                          \
    do {                                                                         \
        gload_lds16(Kp + (size_t)((t) * 64 + srow) * NH + skb,                   \
                    (char*)(&K2[buf][0]) + ((0 * 256 + (w << 6)) << 4));         \
        gload_lds16(Kp + (size_t)((t) * 64 + srow + 32) * NH + skb1,             \
                    (char*)(&K2[buf][0]) + ((1 * 256 + (w << 6)) << 4));         \
    } while (0)
#define STAGE_V(t, buf)                                                          \
    do {                                                                         \
        gload_lds16(Vp + (size_t)srow * SS + (t) * 64 + skb,                     \
                    (char*)(&V2[buf][0]) + ((0 * 256 + (w << 6)) << 4));         \
        gload_lds16(Vp + (size_t)(srow + 32) * SS + (t) * 64 + skb1,             \
                    (char*)(&V2[buf][0]) + ((1 * 256 + (w << 6)) << 4));         \
    } while (0)

    float inv[2][4] = {{0.f, 0.f, 0.f, 0.f}, {0.f, 0.f, 0.f, 0.f}};

    // ---- pass 1: exp2-sums (Q pre-scaled by QK_ALPHA) ----
    STAGE_K(0, 0);
    __syncthreads();
    for (int t = 0; t < 16; ++t) {
        const int cur = t & 1;
        if (t < 15) STAGE_K(t + 1, cur ^ 1);
        f32x4 acc[2][4];
        #pragma unroll
        for (int i = 0; i < 2; ++i)
            #pragma unroll
            for (int j = 0; j < 4; ++j) acc[i][j] = (f32x4){0.f, 0.f, 0.f, 0.f};
        #pragma unroll
        for (int kk = 0; kk < 2; ++kk)
            #pragma unroll
            for (int j = 0; j < 4; ++j) {
                int row = j * 16 + lr;
                bf16x8 bk2 = *(const bf16x8*)&K2[cur][row * 64 + ((lk * 8 + kk * 32) ^ ((row & 7) * 8))];
                acc[0][j] = MFMA16(aq[0][kk], bk2, acc[0][j]);   // bk2 reused: 2 MFMAs
                acc[1][j] = MFMA16(aq[1][kk], bk2, acc[1][j]);   // per LDS fragment read
            }
        #pragma unroll
        for (int i = 0; i < 2; ++i)
            #pragma unroll
            for (int rr = 0; rr < 4; ++rr)
                inv[i][rr] += __builtin_amdgcn_exp2f(acc[i][0][rr]) + __builtin_amdgcn_exp2f(acc[i][1][rr])
                            + __builtin_amdgcn_exp2f(acc[i][2][rr]) + __builtin_amdgcn_exp2f(acc[i][3][rr]);
        __syncthreads();
    }
    #pragma unroll
    for (int i = 0; i < 2; ++i)
        #pragma unroll
        for (int rr = 0; rr < 4; ++rr) {
            float s = inv[i][rr];
            s += __shfl_xor(s, 1);
            s += __shfl_xor(s, 2);
            s += __shfl_xor(s, 4);
            s += __shfl_xor(s, 8);
            inv[i][rr] = 1.0f / s;
        }

    // ---- pass 2: recompute, PV accumulate, emit attn from Psw ----
    f32x4 occ[2][4];
    #pragma unroll
    for (int i = 0; i < 2; ++i)
        #pragma unroll
        for (int j = 0; j < 4; ++j) occ[i][j] = (f32x4){0.f, 0.f, 0.f, 0.f};
    float* Ob = attn + (((size_t)b * HH + h) * LL + r0 + w * 32) * SS;
    const int erow = lane >> 3;          // 0..7; rows rl = erow + hh*8, hh in [0,4)
    const int eseg = lane & 7;

    STAGE_K(0, 0);
    STAGE_V(0, 0);
    __syncthreads();
    for (int t = 0; t < 16; ++t) {
        const int cur = t & 1;
        if (t < 15) { STAGE_K(t + 1, cur ^ 1); STAGE_V(t + 1, cur ^ 1); }
        f32x4 acc[2][4];
        #pragma unroll
        for (int i = 0; i < 2; ++i)
            #pragma unroll
            for (int j = 0; j < 4; ++j) acc[i][j] = (f32x4){0.f, 0.f, 0.f, 0.f};
        #pragma unroll
        for (int kk = 0; kk < 2; ++kk)
            #pragma unroll
            for (int j = 0; j < 4; ++j) {
                int row = j * 16 + lr;
                bf16x8 bk2 = *(const bf16x8*)&K2[cur][row * 64 + ((lk * 8 + kk * 32) ^ ((row & 7) * 8))];
                acc[0][j] = MFMA16(aq[0][kk], bk2, acc[0][j]);
                acc[1][j] = MFMA16(aq[1][kk], bk2, acc[1][j]);
            }
        // normalized bf16 P tile (per-wave LDS region; wave-coherent)
        #pragma unroll
        for (int i = 0; i < 2; ++i)
            #pragma unroll
            for (int j = 0; j < 4; ++j)
                #pragma unroll
                for (int rr = 0; rr < 4; ++rr) {
                    int ql = i * 16 + lk * 4 + rr;
                    float pv = __builtin_amdgcn_exp2f(acc[i][j][rr]) * inv[i][rr];
                    Psw[ql * 64 + ((j * 16 + lr) ^ ((ql & 7) * 8))] = f2b(pv);
                }
        // PV MFMA from Psw / V tile (bv reused across the 2 subtiles)
        #pragma unroll
        for (int kk = 0; kk < 2; ++kk) {
            bf16x8 pa0 = *(const bf16x8*)&Psw[lr * 64 + ((kk * 32 + lk * 8) ^ ((lr & 7) * 8))];
            bf16x8 pa1 = *(const bf16x8*)&Psw[(16 + lr) * 64 + ((kk * 32 + lk * 8) ^ ((lr & 7) * 8))];
            #pragma unroll
            for (int j = 0; j < 4; ++j) {
                int row = j * 16 + lr;
                bf16x8 bv2 = *(const bf16x8*)&V2[cur][row * 64 + ((kk * 32 + lk * 8) ^ ((row & 7) * 8))];
                occ[0][j] = MFMA16(pa0, bv2, occ[0][j]);
                occ[1][j] = MFMA16(pa1, bv2, occ[1][j]);
            }
        }
        // emit attn rows (32 per wave) from Psw as float4 pairs
        float* Obt = Ob + t * 64;
        #pragma unroll
        for (int hh = 0; hh < 4; ++hh) {
            int rl = erow + hh * 8;
            bf16x8 p8 = *(const bf16x8*)&Psw[rl * 64 + ((eseg * 8) ^ ((rl & 7) * 8))];
            float4 o0 = make_float4(b2f((ushort_t)p8[0]), b2f((ushort_t)p8[1]),
                                    b2f((ushort_t)p8[2]), b2f((ushort_t)p8[3]));
            float4 o1 = make_float4(b2f((ushort_t)p8[4]), b2f((ushort_t)p8[5]),
                                    b2f((ushort_t)p8[6]), b2f((ushort_t)p8[7]));
            *(float4*)(Obt + (size_t)rl * SS + eseg * 8) = o0;
            *(float4*)(Obt + (size_t)rl * SS + eseg * 8 + 4) = o1;
        }
        __syncthreads();
    }

    #pragma unroll
    for (int i = 0; i < 2; ++i)
        #pragma unroll
        for (int j = 0; j < 4; ++j)
            #pragma unroll
            for (int rr = 0; rr < 4; ++rr)
                ctx[((size_t)b * LL + r0 + w * 32 + i * 16 + lk * 4 + rr) * NH + h * DKH + j * 16 + lr]
                    = f2b(occ[i][j][rr]);
#undef STAGE_K
#undef STAGE_V
}

// ---------------------------------------------------------------------------
// Output projection: out[i][d] = sum_n ctx[i][n]*Wo2[d][n] + b_o[d]
// ---------------------------------------------------------------------------
__global__ __launch_bounds__(256) void out_gemm(
    const ushort_t* __restrict__ A, const ushort_t* __restrict__ B,
    const float* __restrict__ bias, float* __restrict__ C)
{
    __shared__ ushort_t As[128 * 64];
    __shared__ ushort_t Bs[64 * 64];
    const int p  = xcd_swz(blockIdx.x, gridDim.x);
    const int bm = (p >> 4) * 128;
    const int bn = (p & 15) * 64;
    const int tid = threadIdx.x;
    const int lane = tid & 63;
    const int w = tid >> 6;
    const int wr = w >> 1, wc = w & 1;
    const int lr = lane & 15, lk = lane >> 4;

    f32x4 acc[4][2];
    #pragma unroll
    for (int i = 0; i < 4; ++i)
        #pragma unroll
        for (int j = 0; j < 2; ++j)
            acc[i][j] = (f32x4){0.f, 0.f, 0.f, 0.f};

    for (int k0 = 0; k0 < 1024; k0 += 64) {
        #pragma unroll
        for (int pp = 0; pp < 4; ++pp) {
            int f = pp * 256 + tid;
            int row = f >> 3, seg = f & 7;
            int kb2 = (seg * 8) ^ ((row & 7) * 8);
            gload_lds16(A + (size_t)(bm + row) * 1024 + k0 + kb2,
                        (char*)As + ((pp * 256 + (w << 6)) << 4));
        }
        #pragma unroll
        for (int pp = 0; pp < 2; ++pp) {
            int f = pp * 256 + tid;
            int row = f >> 3, seg = f & 7;
            int kb2 = (seg * 8) ^ ((row & 7) * 8);
            gload_lds16(B + (size_t)(bn + row) * 1024 + k0 + kb2,
                        (char*)Bs + ((pp * 256 + (w << 6)) << 4));
        }
        __syncthreads();
        #pragma unroll
        for (int kk = 0; kk < 2; ++kk) {
            bf16x8 af[4], bfr[2];
            #pragma unroll
            for (int i = 0; i < 4; ++i) {
                int row = wr * 64 + i * 16 + lr;
                af[i] = *(const bf16x8*)&As[row * 64 + ((lk * 8 + kk * 32) ^ ((row & 7) * 8))];
            }
            #pragma unroll
            for (int j = 0; j < 2; ++j) {
                int row = wc * 32 + j * 16 + lr;
                bfr[j] = *(const bf16x8*)&Bs[row * 64 + ((lk * 8 + kk * 32) ^ ((row & 7) * 8))];
            }
            #pragma unroll
            for (int i = 0; i < 4; ++i)
                #pragma unroll
                for (int j = 0; j < 2; ++j)
                    acc[i][j] = MFMA16(af[i], bfr[j], acc[i][j]);
        }
        __syncthreads();
    }

    #pragma unroll
    for (int i = 0; i < 4; ++i)
        #pragma unroll
        for (int j = 0; j < 2; ++j)
            #pragma unroll
            for (int rr = 0; rr < 4; ++rr) {
                int row = bm + wr * 64 + i * 16 + lk * 4 + rr;
                int col = bn + wc * 32 + j * 16 + lr;
                C[(size_t)row * DM + col] = acc[i][j][rr] + bias[col];
            }
}

// ---------------------------------------------------------------------------
extern "C" void kernel_launch(void* const* d_in, const int* in_sizes, int n_in,
                              void* d_out, int out_size, void* d_ws, size_t ws_size,
                              hipStream_t stream)
{
    const float* queries = (const float*)d_in[0];
    const float* keys    = (const float*)d_in[1];
    const float* values  = (const float*)d_in[2];
    const float* gate    = (const float*)d_in[3];
    const float* W_q     = (const float*)d_in[4];
    const float* b_q     = (const float*)d_in[5];
    const float* W_k     = (const float*)d_in[6];
    const float* b_k     = (const float*)d_in[7];
    const float* W_v     = (const float*)d_in[8];
    const float* b_v     = (const float*)d_in[9];
    const float* W_o     = (const float*)d_in[10];
    const float* b_o     = (const float*)d_in[11];

    float* out  = (float*)d_out;                        // [B,L,DM]
    float* attn = out + (size_t)BB * LL * DM;           // [B,H,L,S]

    char* ws = (char*)d_ws;
    const size_t U = (size_t)8 << 20;
    ushort_t* Xq = (ushort_t*)(ws);
    ushort_t* Xk = (ushort_t*)(ws + 1 * U);
    ushort_t* Xv = (ushort_t*)(ws + 2 * U);
    ushort_t* Gq = (ushort_t*)(ws + 3 * U);
    ushort_t* Gk = (ushort_t*)(ws + 4 * U);
    ushort_t* Gv = (ushort_t*)(ws + 5 * U);
    ushort_t* Vt = (ushort_t*)(ws + 6 * U);
    const bool big = ws_size >= 9 * U + ((size_t)2 << 20);
    ushort_t *Qb, *Kb, *Wo2;
    if (big) { Qb = (ushort_t*)(ws + 7 * U); Kb = (ushort_t*)(ws + 8 * U); Wo2 = (ushort_t*)(ws + 9 * U); }
    else     { Qb = Xv; Kb = Gv; Wo2 = (ushort_t*)(ws + 7 * U); }
    ushort_t* ctx = Xq;     // Xq dead after Q-GEMM

    dim3 blk(256, 1, 1);
    prep_kernel<<<2048, blk, 0, stream>>>(queries, keys, values, gate,
                                          W_q, W_k, W_v, W_o,
                                          Xq, Xk, Xv, Gq, Gk, Gv, Wo2);
    if (big) {
        qkv_gemm<<<768, blk, 0, stream>>>(Xq, Gq, b_q, Xk, Gk, b_k,
                                          Xv, Gv, b_v, Qb, Kb, Vt, 0);
    } else {
        // Vt first (reads Xv,Gv), then Q/K merged writing into dead Xv/Gv slots
        qkv_gemm<<<256, blk, 0, stream>>>(Xq, Gq, b_q, Xk, Gk, b_k,
                                          Xv, Gv, b_v, Qb, Kb, Vt, 2);
        qkv_gemm<<<512, blk, 0, stream>>>(Xq, Gq, b_q, Xk, Gk, b_k,
                                          Xv, Gv, b_v, Qb, Kb, Vt, 1);
    }
    fused_attn_kernel<<<512, blk, 0, stream>>>(Qb, Kb, Vt, attn, ctx);
    out_gemm<<<512, blk, 0, stream>>>(ctx, Wo2, b_o, out);
}

// Round 12
// 169.374 us; speedup vs baseline: 1.0783x; 1.0783x over previous
//
#include <hip/hip_runtime.h>
#include <math.h>

#define BB 4
#define LL 1024
#define SS 1024
#define DM 1024
#define HH 16
#define DKH 64
#define NH 1024
#define QK_ALPHA 0.1803368801f   // 0.125 * log2(e); folded into Q so exp = exp2

typedef __attribute__((ext_vector_type(8))) short bf16x8;
typedef __attribute__((ext_vector_type(4))) float f32x4;
typedef unsigned short ushort_t;
typedef unsigned int uint_t;

#define MFMA16(a, b, c) __builtin_amdgcn_mfma_f32_16x16x32_bf16((a), (b), (c), 0, 0, 0)

__device__ __forceinline__ ushort_t f2b(float f) {
    union { float f; uint_t u; } x; x.f = f;
    uint_t r = x.u + 0x7fffu + ((x.u >> 16) & 1u);   // RNE to bf16
    return (ushort_t)(r >> 16);
}

__device__ __forceinline__ float b2f(ushort_t v) {
    union { float f; uint_t u; } x; x.u = ((uint_t)v) << 16;
    return x.f;
}

__device__ __forceinline__ void gload_lds16(const void* g, void* l) {
    __builtin_amdgcn_global_load_lds(
        (const __attribute__((address_space(1))) unsigned int*)g,
        (__attribute__((address_space(3))) unsigned int*)l, 16, 0, 0);
}

// Bijective XCD swizzle (nwg % 8 == 0)
__device__ __forceinline__ int xcd_swz(int lin, int nwg) {
    return (lin & 7) * (nwg >> 3) + (lin >> 3);
}

// ---------------------------------------------------------------------------
// Prep: fp32 -> bf16; gate read ONCE serving all three gated weights.
// ---------------------------------------------------------------------------
__device__ __forceinline__ void cvt8(const float* src, ushort_t* dst, const float* g2) {
    float4 a  = *(const float4*)(src);
    float4 b4 = *(const float4*)(src + 4);
    if (g2) {
        float4 ga = *(const float4*)(g2);
        float4 gb = *(const float4*)(g2 + 4);
        a.x *= ga.x; a.y *= ga.y; a.z *= ga.z; a.w *= ga.w;
        b4.x *= gb.x; b4.y *= gb.y; b4.z *= gb.z; b4.w *= gb.w;
    }
    uint4 o;
    o.x = f2b(a.x)  | ((uint_t)f2b(a.y)  << 16);
    o.y = f2b(a.z)  | ((uint_t)f2b(a.w)  << 16);
    o.z = f2b(b4.x) | ((uint_t)f2b(b4.y) << 16);
    o.w = f2b(b4.z) | ((uint_t)f2b(b4.w) << 16);
    *(uint4*)dst = o;
}

__global__ __launch_bounds__(256) void prep_kernel(
    const float* __restrict__ q, const float* __restrict__ k, const float* __restrict__ v,
    const float* __restrict__ gate,
    const float* __restrict__ Wq, const float* __restrict__ Wk, const float* __restrict__ Wv,
    const float* __restrict__ Wo,
    ushort_t* __restrict__ Xq, ushort_t* __restrict__ Xk, ushort_t* __restrict__ Xv,
    ushort_t* __restrict__ Gq, ushort_t* __restrict__ Gk, ushort_t* __restrict__ Gv,
    ushort_t* __restrict__ Wo2)
{
    const int XCH = 3 * 524288;
    const int GCH = 524288;
    const int WCH = 131072;
    for (int c = blockIdx.x * 256 + threadIdx.x; c < XCH + GCH + WCH; c += gridDim.x * 256) {
        if (c < XCH) {
            int r = c >> 19;
            int e = (c & 524287) * 8;
            cvt8((r == 0 ? q : r == 1 ? k : v) + e,
                 (r == 0 ? Xq : r == 1 ? Xk : Xv) + e, nullptr);
        } else if (c < XCH + GCH) {
            int e = (c - XCH) * 8;          // e = b*1048576 + nm
            int nm = e & 1048575;
            const float* g2 = gate + e;
            cvt8(Wq + nm, Gq + e, g2);
            cvt8(Wk + nm, Gk + e, g2);
            cvt8(Wv + nm, Gv + e, g2);
        } else {
            int e = (c - XCH - GCH) * 8;
            cvt8(Wo + e, Wo2 + e, nullptr);
        }
    }
}

// ---------------------------------------------------------------------------
// Merged Q/K/Vt GEMM, 1-D grid + XCD chunking. 128x128 tile, BK=64, 4 waves.
// Q output (g==0) pre-scaled by QK_ALPHA so attn's exp is a bare exp2.
// ---------------------------------------------------------------------------
__global__ __launch_bounds__(256) void qkv_gemm(
    const ushort_t* __restrict__ Xq, const ushort_t* __restrict__ Gq, const float* __restrict__ bq,
    const ushort_t* __restrict__ Xk, const ushort_t* __restrict__ Gk, const float* __restrict__ bk,
    const ushort_t* __restrict__ Xv, const ushort_t* __restrict__ Gv, const float* __restrict__ bv,
    ushort_t* __restrict__ Qb, ushort_t* __restrict__ Kb, ushort_t* __restrict__ Vt,
    int mode)
{
    __shared__ ushort_t As[128 * 64];
    __shared__ ushort_t Bs[128 * 64];
    const int p  = xcd_swz(blockIdx.x, gridDim.x);
    const int g2 = p >> 6;
    const int r  = p & 63;
    int b, g;
    if (mode == 0)      { b = g2 / 3;  g = g2 % 3; }
    else if (mode == 1) { b = g2 >> 1; g = g2 & 1; }
    else                { b = g2;      g = 2;      }
    const size_t off = (size_t)b * 1048576;
    const ushort_t *A, *B; const float* bias; ushort_t* C; bool brow;
    if (g == 0)      { A = Xq + off; B = Gq + off; bias = bq; C = Qb + off; brow = false; }
    else if (g == 1) { A = Xk + off; B = Gk + off; bias = bk; C = Kb + off; brow = false; }
    else             { A = Gv + off; B = Xv + off; bias = bv; C = Vt + off; brow = true;  }
    const float oscale = (g == 0) ? QK_ALPHA : 1.0f;

    const int bm = (r >> 3) * 128;
    const int bn = (r & 7) * 128;
    const int tid = threadIdx.x;
    const int lane = tid & 63;
    const int w = tid >> 6;
    const int wr = w >> 1, wc = w & 1;
    const int lr = lane & 15, lk = lane >> 4;

    f32x4 acc[4][4];
    #pragma unroll
    for (int i = 0; i < 4; ++i)
        #pragma unroll
        for (int j = 0; j < 4; ++j)
            acc[i][j] = (f32x4){0.f, 0.f, 0.f, 0.f};

    for (int k0 = 0; k0 < 1024; k0 += 64) {
        #pragma unroll
        for (int pp = 0; pp < 4; ++pp) {
            int f = pp * 256 + tid;
            int row = f >> 3, seg = f & 7;
            int kb2 = (seg * 8) ^ ((row & 7) * 8);
            gload_lds16(A + (size_t)(bm + row) * 1024 + k0 + kb2,
                        (char*)As + ((pp * 256 + (w << 6)) << 4));
            gload_lds16(B + (size_t)(bn + row) * 1024 + k0 + kb2,
                        (char*)Bs + ((pp * 256 + (w << 6)) << 4));
        }
        __syncthreads();
        #pragma unroll
        for (int kk = 0; kk < 2; ++kk) {
            bf16x8 af[4], bfr[4];
            #pragma unroll
            for (int i = 0; i < 4; ++i) {
                int row = wr * 64 + i * 16 + lr;
                af[i] = *(const bf16x8*)&As[row * 64 + ((lk * 8 + kk * 32) ^ ((row & 7) * 8))];
            }
            #pragma unroll
            for (int j = 0; j < 4; ++j) {
                int row = wc * 64 + j * 16 + lr;
                bfr[j] = *(const bf16x8*)&Bs[row * 64 + ((lk * 8 + kk * 32) ^ ((row & 7) * 8))];
            }
            #pragma unroll
            for (int i = 0; i < 4; ++i)
                #pragma unroll
                for (int j = 0; j < 4; ++j)
                    acc[i][j] = MFMA16(af[i], bfr[j], acc[i][j]);
        }
        __syncthreads();
    }

    #pragma unroll
    for (int i = 0; i < 4; ++i)
        #pragma unroll
        for (int j = 0; j < 4; ++j)
            #pragma unroll
            for (int rr = 0; rr < 4; ++rr) {
                int row = bm + wr * 64 + i * 16 + lk * 4 + rr;
                int col = bn + wc * 64 + j * 16 + lr;
                float vv = (acc[i][j][rr] + bias[brow ? row : col]) * oscale;
                C[(size_t)row * 1024 + col] = f2b(vv);
            }
}

// ---------------------------------------------------------------------------
// Fused QK^T + softmax + attn-write + PV. 8 waves x 16 q-rows, KVBLK=128:
// 8 barrier intervals per pass (vs 16 at KVBLK=64) — halves the fixed
// per-interval cost (vmcnt drain + wave skew) of this latency-bound kernel.
// Each interval processes two 64-wide s-halves back-to-back.
// K2: [128 s][64 dk] (128B rows). V2: [64 dk][128 s] (256B rows, swizzle
// re-derived: XOR (row&7)*8 within the low-64 col space, bijective).
// LDS: 2*16K + 2*16K + 16K = 80KB -> 2 blocks/CU.
// ---------------------------------------------------------------------------
__global__ __launch_bounds__(512) void fused_attn_kernel(
    const ushort_t* __restrict__ Q, const ushort_t* __restrict__ Kmat,
    const ushort_t* __restrict__ Vt, float* __restrict__ attn,
    ushort_t* __restrict__ ctx)
{
    __shared__ ushort_t K2[2][128 * 64];
    __shared__ ushort_t V2[2][64 * 128];
    __shared__ ushort_t Ps[8 * 1024];
    const int p  = xcd_swz(blockIdx.x, gridDim.x);
    const int bh = p >> 3;
    const int b  = bh >> 4;
    const int h  = bh & 15;
    const int r0 = (p & 7) * 128;
    const int tid = threadIdx.x, lane = tid & 63, w = tid >> 6;
    const int lr = lane & 15, lk = lane >> 4;

    bf16x8 aq[2];
    {
        const ushort_t* Qrow = Q + ((size_t)b * LL + r0 + w * 16 + lr) * NH + h * DKH;
        aq[0] = *(const bf16x8*)(Qrow + lk * 8);
        aq[1] = *(const bf16x8*)(Qrow + lk * 8 + 32);
    }
    const ushort_t* Kp = Kmat + (size_t)b * SS * NH + h * DKH;       // [s][dk], stride NH
    const ushort_t* Vp = Vt + ((size_t)b * NH + h * DKH) * SS;       // [dk][s], stride SS
    ushort_t* Psw = Ps + w * 1024;

    // K staging: 128 rows x 128B; issue p covers rows p*64 + (tid>>3)
    const int srow = tid >> 3;           // 0..63
    const int sseg = tid & 7;
    const int skb  = (sseg * 8) ^ ((srow & 7) * 8);
    // V staging: 64 rows x 256B; issue p covers rows p*32 + (tid>>4)
    const int vrow = tid >> 4;           // 0..31
    const int vseg = tid & 15;
    const int vkb  = (vseg * 8) ^ ((vrow & 7) * 8);   // pre-swizzled source col (bijective: XOR low-64 space)

#define STAGE_K(t, buf)                                                          \
    do {                                                                         \
        gload_lds16(Kp + (size_t)((t) * 128 + srow) * NH + skb,                  \
                    (char*)(&K2[buf][0]) + (w << 10));                           \
        gload_lds16(Kp + (size_t)((t) * 128 + 64 + srow) * NH + skb,             \
                    (char*)(&K2[buf][0]) + 8192 + (w << 10));                    \
    } while (0)
#define STAGE_V(t, buf)                                                          \
    do {                                                                         \
        gload_lds16(Vp + (size_t)vrow * SS + (t) * 128 + vkb,                    \
                    (char*)(&V2[buf][0]) + (w << 10));                           \
        gload_lds16(Vp + (size_t)(vrow + 32) * SS + (t) * 128 + vkb,             \
                    (char*)(&V2[buf][0]) + 8192 + (w << 10));                    \
    } while (0)

    float inv[4] = {0.f, 0.f, 0.f, 0.f};

    // ---- pass 1: exp2-sums (Q pre-scaled by QK_ALPHA), 8 intervals ----
    STAGE_K(0, 0);
    __syncthreads();
    for (int t = 0; t < 8; ++t) {
        const int cur = t & 1;
        if (t < 7) STAGE_K(t + 1, cur ^ 1);
        #pragma unroll
        for (int jh = 0; jh < 2; ++jh) {
            f32x4 acc[4];
            #pragma unroll
            for (int j = 0; j < 4; ++j) acc[j] = (f32x4){0.f, 0.f, 0.f, 0.f};
            #pragma unroll
            for (int kk = 0; kk < 2; ++kk)
                #pragma unroll
                for (int j = 0; j < 4; ++j) {
                    int row = jh * 64 + j * 16 + lr;
                    bf16x8 bk2 = *(const bf16x8*)&K2[cur][row * 64 + ((lk * 8 + kk * 32) ^ ((row & 7) * 8))];
                    acc[j] = MFMA16(aq[kk], bk2, acc[j]);
                }
            #pragma unroll
            for (int rr = 0; rr < 4; ++rr)
                inv[rr] += __builtin_amdgcn_exp2f(acc[0][rr]) + __builtin_amdgcn_exp2f(acc[1][rr])
                         + __builtin_amdgcn_exp2f(acc[2][rr]) + __builtin_amdgcn_exp2f(acc[3][rr]);
        }
        __syncthreads();
    }
    #pragma unroll
    for (int rr = 0; rr < 4; ++rr) {
        float s = inv[rr];
        s += __shfl_xor(s, 1);
        s += __shfl_xor(s, 2);
        s += __shfl_xor(s, 4);
        s += __shfl_xor(s, 8);
        inv[rr] = 1.0f / s;
    }

    // ---- pass 2: recompute, PV accumulate, emit attn; 8 intervals ----
    f32x4 occ[4];
    #pragma unroll
    for (int j = 0; j < 4; ++j) occ[j] = (f32x4){0.f, 0.f, 0.f, 0.f};
    float* Ob = attn + (((size_t)b * HH + h) * LL + r0 + w * 16) * SS;
    const int erow = lane >> 3;          // 0..7, +8 second half
    const int eseg = lane & 7;

    STAGE_K(0, 0);
    STAGE_V(0, 0);
    __syncthreads();
    for (int t = 0; t < 8; ++t) {
        const int cur = t & 1;
        if (t < 7) { STAGE_K(t + 1, cur ^ 1); STAGE_V(t + 1, cur ^ 1); }
        #pragma unroll
        for (int jh = 0; jh < 2; ++jh) {
            f32x4 acc[4];
            #pragma unroll
            for (int j = 0; j < 4; ++j) acc[j] = (f32x4){0.f, 0.f, 0.f, 0.f};
            #pragma unroll
            for (int kk = 0; kk < 2; ++kk)
                #pragma unroll
                for (int j = 0; j < 4; ++j) {
                    int row = jh * 64 + j * 16 + lr;
                    bf16x8 bk2 = *(const bf16x8*)&K2[cur][row * 64 + ((lk * 8 + kk * 32) ^ ((row & 7) * 8))];
                    acc[j] = MFMA16(aq[kk], bk2, acc[j]);
                }
            // normalized bf16 P tile for this 64-s half (per-wave LDS; wave
            // LDS ops are in-order, so write->read->rewrite across halves is safe)
            #pragma unroll
            for (int j = 0; j < 4; ++j)
                #pragma unroll
                for (int rr = 0; rr < 4; ++rr) {
                    int ql = lk * 4 + rr;
                    float pv = __builtin_amdgcn_exp2f(acc[j][rr]) * inv[rr];
                    Psw[ql * 64 + ((j * 16 + lr) ^ ((ql & 7) * 8))] = f2b(pv);
                }
            // PV MFMA from Psw / V2 (V2 row = dk 0..63, col = jh*64 + s-local)
            #pragma unroll
            for (int kk = 0; kk < 2; ++kk) {
                bf16x8 pa = *(const bf16x8*)&Psw[lr * 64 + ((kk * 32 + lk * 8) ^ ((lr & 7) * 8))];
                #pragma unroll
                for (int j = 0; j < 4; ++j) {
                    int row = j * 16 + lr;
                    bf16x8 bv2 = *(const bf16x8*)&V2[cur][row * 128 + ((jh * 64 + kk * 32 + lk * 8) ^ ((row & 7) * 8))];
                    occ[j] = MFMA16(pa, bv2, occ[j]);
                }
            }
            // emit attn rows from Psw as float4 pairs (8 lanes = 256B rows)
            float* Obt = Ob + t * 128 + jh * 64;
            #pragma unroll
            for (int hh = 0; hh < 2; ++hh) {
                int rl = erow + hh * 8;
                bf16x8 p8 = *(const bf16x8*)&Psw[rl * 64 + ((eseg * 8) ^ ((rl & 7) * 8))];
                float4 o0 = make_float4(b2f((ushort_t)p8[0]), b2f((ushort_t)p8[1]),
                                        b2f((ushort_t)p8[2]), b2f((ushort_t)p8[3]));
                float4 o1 = make_float4(b2f((ushort_t)p8[4]), b2f((ushort_t)p8[5]),
                                        b2f((ushort_t)p8[6]), b2f((ushort_t)p8[7]));
                *(float4*)(Obt + (size_t)rl * SS + eseg * 8) = o0;
                *(float4*)(Obt + (size_t)rl * SS + eseg * 8 + 4) = o1;
            }
        }
        __syncthreads();
    }

    #pragma unroll
    for (int j = 0; j < 4; ++j)
        #pragma unroll
        for (int rr = 0; rr < 4; ++rr)
            ctx[((size_t)b * LL + r0 + w * 16 + lk * 4 + rr) * NH + h * DKH + j * 16 + lr]
                = f2b(occ[j][rr]);
#undef STAGE_K
#undef STAGE_V
}

// ---------------------------------------------------------------------------
// Output projection: out[i][d] = sum_n ctx[i][n]*Wo2[d][n] + b_o[d]
// ---------------------------------------------------------------------------
__global__ __launch_bounds__(256) void out_gemm(
    const ushort_t* __restrict__ A, const ushort_t* __restrict__ B,
    const float* __restrict__ bias, float* __restrict__ C)
{
    __shared__ ushort_t As[128 * 64];
    __shared__ ushort_t Bs[64 * 64];
    const int p  = xcd_swz(blockIdx.x, gridDim.x);
    const int bm = (p >> 4) * 128;
    const int bn = (p & 15) * 64;
    const int tid = threadIdx.x;
    const int lane = tid & 63;
    const int w = tid >> 6;
    const int wr = w >> 1, wc = w & 1;
    const int lr = lane & 15, lk = lane >> 4;

    f32x4 acc[4][2];
    #pragma unroll
    for (int i = 0; i < 4; ++i)
        #pragma unroll
        for (int j = 0; j < 2; ++j)
            acc[i][j] = (f32x4){0.f, 0.f, 0.f, 0.f};

    for (int k0 = 0; k0 < 1024; k0 += 64) {
        #pragma unroll
        for (int pp = 0; pp < 4; ++pp) {
            int f = pp * 256 + tid;
            int row = f >> 3, seg = f & 7;
            int kb2 = (seg * 8) ^ ((row & 7) * 8);
            gload_lds16(A + (size_t)(bm + row) * 1024 + k0 + kb2,
                        (char*)As + ((pp * 256 + (w << 6)) << 4));
        }
        #pragma unroll
        for (int pp = 0; pp < 2; ++pp) {
            int f = pp * 256 + tid;
            int row = f >> 3, seg = f & 7;
            int kb2 = (seg * 8) ^ ((row & 7) * 8);
            gload_lds16(B + (size_t)(bn + row) * 1024 + k0 + kb2,
                        (char*)Bs + ((pp * 256 + (w << 6)) << 4));
        }
        __syncthreads();
        #pragma unroll
        for (int kk = 0; kk < 2; ++kk) {
            bf16x8 af[4], bfr[2];
            #pragma unroll
            for (int i = 0; i < 4; ++i) {
                int row = wr * 64 + i * 16 + lr;
                af[i] = *(const bf16x8*)&As[row * 64 + ((lk * 8 + kk * 32) ^ ((row & 7) * 8))];
            }
            #pragma unroll
            for (int j = 0; j < 2; ++j) {
                int row = wc * 32 + j * 16 + lr;
                bfr[j] = *(const bf16x8*)&Bs[row * 64 + ((lk * 8 + kk * 32) ^ ((row & 7) * 8))];
            }
            #pragma unroll
            for (int i = 0; i < 4; ++i)
                #pragma unroll
                for (int j = 0; j < 2; ++j)
                    acc[i][j] = MFMA16(af[i], bfr[j], acc[i][j]);
        }
        __syncthreads();
    }

    #pragma unroll
    for (int i = 0; i < 4; ++i)
        #pragma unroll
        for (int j = 0; j < 2; ++j)
            #pragma unroll
            for (int rr = 0; rr < 4; ++rr) {
                int row = bm + wr * 64 + i * 16 + lk * 4 + rr;
                int col = bn + wc * 32 + j * 16 + lr;
                C[(size_t)row * DM + col] = acc[i][j][rr] + bias[col];
            }
}

// ---------------------------------------------------------------------------
extern "C" void kernel_launch(void* const* d_in, const int* in_sizes, int n_in,
                              void* d_out, int out_size, void* d_ws, size_t ws_size,
                              hipStream_t stream)
{
    const float* queries = (const float*)d_in[0];
    const float* keys    = (const float*)d_in[1];
    const float* values  = (const float*)d_in[2];
    const float* gate    = (const float*)d_in[3];
    const float* W_q     = (const float*)d_in[4];
    const float* b_q     = (const float*)d_in[5];
    const float* W_k     = (const float*)d_in[6];
    const float* b_k     = (const float*)d_in[7];
    const float* W_v     = (const float*)d_in[8];
    const float* b_v     = (const float*)d_in[9];
    const float* W_o     = (const float*)d_in[10];
    const float* b_o     = (const float*)d_in[11];

    float* out  = (float*)d_out;                        // [B,L,DM]
    float* attn = out + (size_t)BB * LL * DM;           // [B,H,L,S]

    char* ws = (char*)d_ws;
    const size_t U = (size_t)8 << 20;
    ushort_t* Xq = (ushort_t*)(ws);
    ushort_t* Xk = (ushort_t*)(ws + 1 * U);
    ushort_t* Xv = (ushort_t*)(ws + 2 * U);
    ushort_t* Gq = (ushort_t*)(ws + 3 * U);
    ushort_t* Gk = (ushort_t*)(ws + 4 * U);
    ushort_t* Gv = (ushort_t*)(ws + 5 * U);
    ushort_t* Vt = (ushort_t*)(ws + 6 * U);
    const bool big = ws_size >= 9 * U + ((size_t)2 << 20);
    ushort_t *Qb, *Kb, *Wo2;
    if (big) { Qb = (ushort_t*)(ws + 7 * U); Kb = (ushort_t*)(ws + 8 * U); Wo2 = (ushort_t*)(ws + 9 * U); }
    else     { Qb = Xv; Kb = Gv; Wo2 = (ushort_t*)(ws + 7 * U); }
    ushort_t* ctx = Xq;     // Xq dead after Q-GEMM

    dim3 blk(256, 1, 1);
    prep_kernel<<<2048, blk, 0, stream>>>(queries, keys, values, gate,
                                          W_q, W_k, W_v, W_o,
                                          Xq, Xk, Xv, Gq, Gk, Gv, Wo2);
    if (big) {
        qkv_gemm<<<768, blk, 0, stream>>>(Xq, Gq, b_q, Xk, Gk, b_k,
                                          Xv, Gv, b_v, Qb, Kb, Vt, 0);
    } else {
        // Vt first (reads Xv,Gv), then Q/K merged writing into dead Xv/Gv slots
        qkv_gemm<<<256, blk, 0, stream>>>(Xq, Gq, b_q, Xk, Gk, b_k,
                                          Xv, Gv, b_v, Qb, Kb, Vt, 2);
        qkv_gemm<<<512, blk, 0, stream>>>(Xq, Gq, b_q, Xk, Gk, b_k,
                                          Xv, Gv, b_v, Qb, Kb, Vt, 1);
    }
    fused_attn_kernel<<<512, dim3(512, 1, 1), 0, stream>>>(Qb, Kb, Vt, attn, ctx);
    out_gemm<<<512, blk, 0, stream>>>(ctx, Wo2, b_o, out);
}